// Round 11
// baseline (107.919 us; speedup 1.0000x reference)
//
#include <hip/hip_runtime.h>

// URGCN layer, MI355X — round 11.
// r10 post-mortem: __shfl inside half-divergent loop boundaries reads
// INACTIVE source lanes (ds_bpermute -> undefined) when the two 32-lane
// halves' trip counts differ -> garbage messages (absmax 3.99). Fix: wave-
// uniform batch loop, shfls hoisted to full-activity points, only guarded
// loads diverge in the tail batch. fill+ts fusion retained (race-free).
//
// Algebra: msg_agg = (Σ_e T[src] + u[rel]) / deg, T = h@Wn (bf16 MFMA),
//          u = rel@Wn.  out = Sp + msg_agg, Sp = h@(I+Wself) (f32, in d_out).

constexpr int NNODES = 50000;
constexpr int NEDGES = 600000;
constexpr int NRELS  = 500;
constexpr int DIM    = 128;
constexpr int CAP    = 48;      // bucket capacity per node
constexpr int OCAP   = 8192;    // overflow list capacity

constexpr int NODE_BLKS = (NNODES + 63) / 64;   // 782
constexpr int REL_BLKS  = (NRELS  + 63) / 64;   // 8
constexpr int TS_BLKS   = NODE_BLKS + REL_BLKS; // 790
// interleaved fused grid: every 4th block (bid&3==3) is a ts block
constexpr int FUSED_BLKS = TS_BLKS * 4;         // 3160 (fill ids 0..2369 cover 2344)

constexpr int BP = 136;   // LDS B row pitch (shorts); 272B -> banks spread
constexpr int TP = 136;   // LDS T tile pitch (shorts)
constexpr int SP = 132;   // LDS S tile pitch (floats)

// prep geometry: zero cnt[50000] + ocount (50004 ints -> 12501 int4)
constexpr int WCONV_BLKS = (DIM * DIM + 255) / 256;            // 64
constexpr int ZERO_INT4S = 12501;
constexpr int ZERO_BLKS  = (ZERO_INT4S + 255) / 256;           // 49
constexpr int PREP_BLKS  = WCONV_BLKS + ZERO_BLKS;             // 113

// ---------------- workspace layout (bytes) ----------------
constexpr size_t OFF_CNT_B  = 0;         // int[50000]
constexpr size_t OFF_OCNT_B = 200000;    // int ocount (zeroed with cnt)
constexpr size_t OFF_OBUF_B = 204800;    // uint2[8192]
constexpr size_t OFF_BKT_B  = 270336;    // uint[50000*48] = 9.6 MB
constexpr size_t OFF_BTN_B  = OFF_BKT_B + (size_t)NNODES * CAP * 4;  // Wn^T bf16
constexpr size_t OFF_BTS_B  = OFF_BTN_B + 32768;                     // (I+Ws)^T bf16
constexpr size_t OFF_T_B    = OFF_BTS_B + 32768;                     // ushort[50000*128]
constexpr size_t OFF_U_B    = OFF_T_B + (size_t)NNODES * DIM * 2;    // ushort[500*128]

typedef short s8f __attribute__((ext_vector_type(8)));   // 8 bf16 (4 VGPR)
typedef float f4  __attribute__((ext_vector_type(4)));   // MFMA acc

static __device__ __forceinline__ unsigned short f2bf(float f) {
    unsigned u = __builtin_bit_cast(unsigned, f);
    u += 0x7FFFu + ((u >> 16) & 1u);        // round-to-nearest-even
    return (unsigned short)(u >> 16);
}
static __device__ __forceinline__ float bflo(unsigned v) {
    return __builtin_bit_cast(float, v << 16);
}
static __device__ __forceinline__ float bfhi(unsigned v) {
    return __builtin_bit_cast(float, v & 0xFFFF0000u);
}

// ---------------------------------------------------------------------------
// prep: blocks [0,64) convert weights; blocks [64,113) zero cnt+ocount.
__global__ __launch_bounds__(256) void prep(const float* __restrict__ wn,
                                            const float* __restrict__ wsf,
                                            unsigned short* __restrict__ btn,
                                            unsigned short* __restrict__ bts,
                                            int4* __restrict__ cnt4)
{
    int b = blockIdx.x;
    if (b < WCONV_BLKS) {
        int idx = b * 256 + threadIdx.x;
        int k = idx >> 7, j = idx & 127;
        btn[(size_t)j * DIM + k] = f2bf(wn[idx]);                         // Wn^T
        bts[(size_t)j * DIM + k] = f2bf(wsf[idx] + (k == j ? 1.f : 0.f)); // (I+Ws)^T
    } else {
        int idx = (b - WCONV_BLKS) * 256 + threadIdx.x;
        if (idx < ZERO_INT4S) cnt4[idx] = make_int4(0, 0, 0, 0);
    }
}

// ---------------------------------------------------------------------------
// fused fill+ts. Interleaved roles: (bid&3)==3 -> ts block (tsid = bid>>2),
// else fill block (fillid = bid - (bid+1)/4). Independent work; fill's
// latency-bound scatter overlaps ts's MFMA compute on the same CUs.
// ---------------------------------------------------------------------------
__global__ __launch_bounds__(256, 4) void fill_ts(
    const int* __restrict__ edges,
    int* __restrict__ cnt, unsigned* __restrict__ buckets,
    int* __restrict__ ocount, uint2* __restrict__ obuf,
    const float* __restrict__ nodes, const float* __restrict__ rels,
    const unsigned short* __restrict__ btn, const unsigned short* __restrict__ bts,
    unsigned short* __restrict__ T, unsigned short* __restrict__ U,
    float* __restrict__ Sp)
{
    __shared__ __align__(16) char ldsRaw[DIM * BP * 2];   // 34816 B
    int bid = blockIdx.x;

    if ((bid & 3) != 3) {
        // ---------------- fill role ----------------
        int fillid = bid - ((bid + 1) >> 2);
        int e = fillid * 256 + threadIdx.x;
        if (e >= NEDGES) return;
        int src = edges[e * 3 + 0];
        int rel = edges[e * 3 + 1];
        int dst = edges[e * 3 + 2];
        unsigned packed = (unsigned)src | ((unsigned)rel << 16);
        int pos = atomicAdd(cnt + dst, 1);
        if (pos < CAP) {
            buckets[(size_t)dst * CAP + pos] = packed;
        } else {
            int o = atomicAdd(ocount, 1);
            if (o < OCAP) obuf[o] = make_uint2((unsigned)dst, packed);
        }
        return;
    }

    // ---------------- ts role ----------------
    unsigned short* ldsB = (unsigned short*)ldsRaw;
    unsigned short* ldsT = (unsigned short*)ldsRaw;       // aliased views
    float*          ldsS = (float*)ldsRaw;

    int blk = bid >> 2;
    bool isRel = blk >= NODE_BLKS;
    const float* A = isRel ? rels : nodes;
    int nrows = isRel ? NRELS : NNODES;
    int rowbase = (isRel ? (blk - NODE_BLKS) : blk) * 64;

    int t  = threadIdx.x;
    int wv = t >> 6;
    int l  = t & 63;
    int r0 = rowbase + wv * 16;
    int m  = l & 15;
    int kg = l >> 4;
    int arow  = r0 + m;
    int arowc = arow < nrows ? arow : nrows - 1;

    // A fragments, loaded/converted ONCE for both phases
    s8f afrag[4];
    #pragma unroll
    for (int ks = 0; ks < 4; ++ks) {
        const float* p = A + (size_t)arowc * DIM + ks * 32 + kg * 8;
        float4 x = *(const float4*)p;
        float4 y = *(const float4*)(p + 4);
        s8f a;
        a[0] = (short)f2bf(x.x); a[1] = (short)f2bf(x.y);
        a[2] = (short)f2bf(x.z); a[3] = (short)f2bf(x.w);
        a[4] = (short)f2bf(y.x); a[5] = (short)f2bf(y.y);
        a[6] = (short)f2bf(y.z); a[7] = (short)f2bf(y.w);
        afrag[ks] = a;
    }

    // ---- phase 1: T/U = A @ Wn ----
    #pragma unroll
    for (int i = 0; i < 8; ++i) {                  // stage Wn^T
        int idx = t + i * 256;
        int col = idx >> 4, slot = idx & 15;
        *(uint4*)(ldsB + (size_t)col * BP + slot * 8) =
            *(const uint4*)(btn + (size_t)col * DIM + slot * 8);
    }
    __syncthreads();

    f4 acc[8];
    #pragma unroll
    for (int ct = 0; ct < 8; ++ct) {
        int col = ct * 16 + m;
        const unsigned short* bp = ldsB + (size_t)col * BP + kg * 8;
        f4 a = {0.f, 0.f, 0.f, 0.f};
        #pragma unroll
        for (int ks = 0; ks < 4; ++ks)
            a = __builtin_amdgcn_mfma_f32_16x16x32_bf16(afrag[ks], *(const s8f*)(bp + ks * 32), a, 0, 0, 0);
        acc[ct] = a;
    }
    __syncthreads();   // all ldsB reads done; safe to overwrite as ldsT

    #pragma unroll
    for (int ct = 0; ct < 8; ++ct)
        #pragma unroll
        for (int r = 0; r < 4; ++r)
            ldsT[((size_t)wv * 16 + kg * 4 + r) * TP + ct * 16 + m] = f2bf(acc[ct][r]);
    __syncthreads();

    unsigned short* Tout = isRel ? U : T;
    #pragma unroll
    for (int p = 0; p < 4; ++p) {
        int row = p * 4 + kg;
        int rg  = r0 + row;
        if (rg < nrows)
            *(uint4*)(Tout + (size_t)rg * DIM + m * 8) =
                *(const uint4*)&ldsT[((size_t)wv * 16 + row) * TP + m * 8];
    }
    if (isRel) return;   // whole block is rel -> uniform exit

    __syncthreads();   // ldsT reads done; safe to restage

    // ---- phase 2: Sp = A @ (I+Ws) ----
    #pragma unroll
    for (int i = 0; i < 8; ++i) {                  // stage (I+Ws)^T
        int idx = t + i * 256;
        int col = idx >> 4, slot = idx & 15;
        *(uint4*)(ldsB + (size_t)col * BP + slot * 8) =
            *(const uint4*)(bts + (size_t)col * DIM + slot * 8);
    }
    __syncthreads();

    #pragma unroll
    for (int ct = 0; ct < 8; ++ct) {
        int col = ct * 16 + m;
        const unsigned short* bp = ldsB + (size_t)col * BP + kg * 8;
        f4 a = {0.f, 0.f, 0.f, 0.f};
        #pragma unroll
        for (int ks = 0; ks < 4; ++ks)
            a = __builtin_amdgcn_mfma_f32_16x16x32_bf16(afrag[ks], *(const s8f*)(bp + ks * 32), a, 0, 0, 0);
        acc[ct] = a;
    }
    __syncthreads();   // ldsB reads done; overwrite as ldsS

    #pragma unroll
    for (int ct = 0; ct < 8; ++ct)
        #pragma unroll
        for (int r = 0; r < 4; ++r)
            ldsS[((size_t)wv * 16 + kg * 4 + r) * SP + ct * 16 + m] = acc[ct][r];
    __syncthreads();

    #pragma unroll
    for (int p = 0; p < 4; ++p) {
        int row = p * 4 + kg;
        int rg  = r0 + row;
        if (rg < NNODES) {
            float* orow = Sp + (size_t)rg * DIM;
            #pragma unroll
            for (int j = 0; j < 2; ++j) {
                int c0 = m * 4 + j * 64;
                *(float4*)(orow + c0) =
                    *(const float4*)&ldsS[((size_t)wv * 16 + row) * SP + c0];
            }
        }
    }
}

// ---------------------------------------------------------------------------
// gather: full wave per node. Lane l prefetches bucket entry l (one coalesced
// load). Batch loop trip count is WAVE-UNIFORM (degc uniform per wave); all
// __shfl broadcasts execute at full-wave activity; only the guarded row-load
// accumulates diverge in the tail batch. out = Sp[n] + acc/deg.
// ---------------------------------------------------------------------------
#define ACC1(b) { \
    uint2 tt = *(const uint2*)(T + (size_t)((b) & 0xFFFFu) * DIM + c * 4); \
    uint2 uu = *(const uint2*)(U + (size_t)((b) >> 16)     * DIM + c * 4); \
    acc.x += bflo(tt.x) + bflo(uu.x); acc.y += bfhi(tt.x) + bfhi(uu.x); \
    acc.z += bflo(tt.y) + bflo(uu.y); acc.w += bfhi(tt.y) + bfhi(uu.y); }

__global__ __launch_bounds__(256) void gather(
    const unsigned short* __restrict__ T, const unsigned short* __restrict__ U,
    const int* __restrict__ cnt, const unsigned* __restrict__ buckets,
    const int* __restrict__ ocount, const uint2* __restrict__ obuf,
    const float* __restrict__ nodes, const float* __restrict__ wse,
    float* __restrict__ outp)
{
    int tid = blockIdx.x * 256 + threadIdx.x;
    int n = tid >> 6;
    if (n >= NNODES) return;
    int l = threadIdx.x & 63;
    int half = l >> 5;
    int c = l & 31;

    int deg = cnt[n];    // wave-uniform

    if (deg == 0) {
        // rare (~6e-6 per node): out = h + h @ Wse, straight f32 matvec
        if (half == 0) {
            float s0 = 0, s1 = 0, s2 = 0, s3 = 0;
            for (int k = 0; k < DIM; ++k) {
                float hk = nodes[(size_t)n * DIM + k];
                const float* wr = wse + (size_t)k * DIM + c * 4;
                s0 += hk * wr[0]; s1 += hk * wr[1];
                s2 += hk * wr[2]; s3 += hk * wr[3];
            }
            float4 hv = *(const float4*)(nodes + (size_t)n * DIM + c * 4);
            float4 o = { hv.x + s0, hv.y + s1, hv.z + s2, hv.w + s3 };
            *(float4*)(outp + (size_t)n * DIM + c * 4) = o;
        }
        return;
    }

    int degc = deg < CAP ? deg : CAP;   // wave-uniform
    // lane-parallel bucket prefetch: one coalesced load covers all entries
    unsigned myent = (l < degc) ? buckets[(size_t)n * CAP + l] : 0u;

    float4 acc = make_float4(0.f, 0.f, 0.f, 0.f);
    for (int jb = 0; jb < degc; jb += 8) {      // UNIFORM loop condition
        int j0 = jb + half;
        // shfls at full-wave activity (no divergence here)
        unsigned b0 = __shfl(myent, j0,     64);
        unsigned b1 = __shfl(myent, j0 + 2, 64);
        unsigned b2 = __shfl(myent, j0 + 4, 64);
        unsigned b3 = __shfl(myent, j0 + 6, 64);
        if (jb + 8 <= degc) {                   // UNIFORM: full batch
            ACC1(b0); ACC1(b1); ACC1(b2); ACC1(b3);
        } else {                                // UNIFORM: tail batch
            if (j0     < degc) ACC1(b0);        // divergent guards: loads only
            if (j0 + 2 < degc) ACC1(b1);
            if (j0 + 4 < degc) ACC1(b2);
            if (j0 + 6 < degc) ACC1(b3);
        }
    }

    if (deg > CAP) {                            // wave-uniform, ~never taken
        int oc = *ocount;
        if (oc > OCAP) oc = OCAP;
        for (int k = 0; k < oc; ++k) {
            uint2 e = obuf[k];
            if ((int)e.x == n && (k & 1) == half) {
                unsigned b0 = e.y;
                ACC1(b0);
            }
        }
    }

    acc.x += __shfl_xor(acc.x, 32, 64);
    acc.y += __shfl_xor(acc.y, 32, 64);
    acc.z += __shfl_xor(acc.z, 32, 64);
    acc.w += __shfl_xor(acc.w, 32, 64);

    if (half == 0) {
        float inv = 1.0f / (float)deg;
        float4 sp = *(const float4*)(outp + (size_t)n * DIM + c * 4);
        float4 o = { sp.x + acc.x * inv, sp.y + acc.y * inv,
                     sp.z + acc.z * inv, sp.w + acc.w * inv };
        *(float4*)(outp + (size_t)n * DIM + c * 4) = o;
    }
}

// ---------------------------------------------------------------------------
extern "C" void kernel_launch(void* const* d_in, const int* in_sizes, int n_in,
                              void* d_out, int out_size, void* d_ws, size_t ws_size,
                              hipStream_t stream)
{
    const float* nodes = (const float*)d_in[0];
    const float* rels  = (const float*)d_in[1];
    const int*   edges = (const int*)d_in[2];
    const float* wn    = (const float*)d_in[3];
    const float* wsf   = (const float*)d_in[4];
    const float* wse   = (const float*)d_in[5];
    float* out = (float*)d_out;

    char* ws = (char*)d_ws;
    int*            cnt     = (int*)(ws + OFF_CNT_B);
    int*            ocount  = (int*)(ws + OFF_OCNT_B);
    uint2*          obuf    = (uint2*)(ws + OFF_OBUF_B);
    unsigned*       buckets = (unsigned*)(ws + OFF_BKT_B);
    unsigned short* btn     = (unsigned short*)(ws + OFF_BTN_B);
    unsigned short* bts     = (unsigned short*)(ws + OFF_BTS_B);
    unsigned short* T       = (unsigned short*)(ws + OFF_T_B);
    unsigned short* U       = (unsigned short*)(ws + OFF_U_B);

    prep<<<PREP_BLKS, 256, 0, stream>>>(wn, wsf, btn, bts, (int4*)cnt);

    fill_ts<<<FUSED_BLKS, 256, 0, stream>>>(edges, cnt, buckets, ocount, obuf,
                                            nodes, rels, btn, bts, T, U, out);

    int gb = (NNODES * 64 + 255) / 256;
    gather<<<gb, 256, 0, stream>>>(T, U, cnt, buckets, ocount, obuf, nodes, wse, out);
}

// Round 12
// 96.362 us; speedup vs baseline: 1.1199x; 1.1199x over previous
//
#include <hip/hip_runtime.h>

// URGCN layer, MI355X — round 12.
// r11 post-mortem: fill+ts fusion REGRESSED (58us > 42+9 serial) — the ts
// role's 34.8KB LDS was allocated for every fill block (occupancy cap) and
// ts's 64MB streaming thrashed L2 under fill's atomics. Reverted.
// This round: fill gets 4 edges/thread (3x int4 coalesced loads, 4 independent
// atomic->store chains = ILP for the latency-bound kernel); gather hoists the
// Sp row read off the critical tail.
//
// Algebra: msg_agg = (Σ_e T[src] + u[rel]) / deg, T = h@Wn (bf16 MFMA),
//          u = rel@Wn.  out = Sp + msg_agg, Sp = h@(I+Wself) (f32, in d_out).

constexpr int NNODES = 50000;
constexpr int NEDGES = 600000;
constexpr int NRELS  = 500;
constexpr int DIM    = 128;
constexpr int CAP    = 48;      // bucket capacity per node
constexpr int OCAP   = 8192;    // overflow list capacity

constexpr int NODE_BLKS = (NNODES + 63) / 64;   // 782
constexpr int REL_BLKS  = (NRELS  + 63) / 64;   // 8
constexpr int TS_BLKS   = NODE_BLKS + REL_BLKS; // 790

constexpr int BP = 136;   // LDS B row pitch (shorts); 272B -> banks spread
constexpr int TP = 136;   // LDS T tile pitch (shorts)
constexpr int SP = 132;   // LDS S tile pitch (floats)

// prep geometry: zero cnt[50000] + ocount (50004 ints -> 12501 int4)
constexpr int WCONV_BLKS = (DIM * DIM + 255) / 256;            // 64
constexpr int ZERO_INT4S = 12501;
constexpr int ZERO_BLKS  = (ZERO_INT4S + 255) / 256;           // 49
constexpr int PREP_BLKS  = WCONV_BLKS + ZERO_BLKS;             // 113

// fill geometry: 4 edges/thread, 600000/4 = 150000 threads
constexpr int FILL_THREADS = NEDGES / 4;                       // 150000
constexpr int FILL_BLKS    = (FILL_THREADS + 255) / 256;       // 586

// ---------------- workspace layout (bytes) ----------------
constexpr size_t OFF_CNT_B  = 0;         // int[50000]
constexpr size_t OFF_OCNT_B = 200000;    // int ocount (zeroed with cnt)
constexpr size_t OFF_OBUF_B = 204800;    // uint2[8192]
constexpr size_t OFF_BKT_B  = 270336;    // uint[50000*48] = 9.6 MB
constexpr size_t OFF_BTN_B  = OFF_BKT_B + (size_t)NNODES * CAP * 4;  // Wn^T bf16
constexpr size_t OFF_BTS_B  = OFF_BTN_B + 32768;                     // (I+Ws)^T bf16
constexpr size_t OFF_T_B    = OFF_BTS_B + 32768;                     // ushort[50000*128]
constexpr size_t OFF_U_B    = OFF_T_B + (size_t)NNODES * DIM * 2;    // ushort[500*128]

typedef short s8f __attribute__((ext_vector_type(8)));   // 8 bf16 (4 VGPR)
typedef float f4  __attribute__((ext_vector_type(4)));   // MFMA acc

static __device__ __forceinline__ unsigned short f2bf(float f) {
    unsigned u = __builtin_bit_cast(unsigned, f);
    u += 0x7FFFu + ((u >> 16) & 1u);        // round-to-nearest-even
    return (unsigned short)(u >> 16);
}
static __device__ __forceinline__ float bflo(unsigned v) {
    return __builtin_bit_cast(float, v << 16);
}
static __device__ __forceinline__ float bfhi(unsigned v) {
    return __builtin_bit_cast(float, v & 0xFFFF0000u);
}

// ---------------------------------------------------------------------------
// prep: blocks [0,64) convert weights; blocks [64,113) zero cnt+ocount.
__global__ __launch_bounds__(256) void prep(const float* __restrict__ wn,
                                            const float* __restrict__ wsf,
                                            unsigned short* __restrict__ btn,
                                            unsigned short* __restrict__ bts,
                                            int4* __restrict__ cnt4)
{
    int b = blockIdx.x;
    if (b < WCONV_BLKS) {
        int idx = b * 256 + threadIdx.x;
        int k = idx >> 7, j = idx & 127;
        btn[(size_t)j * DIM + k] = f2bf(wn[idx]);                         // Wn^T
        bts[(size_t)j * DIM + k] = f2bf(wsf[idx] + (k == j ? 1.f : 0.f)); // (I+Ws)^T
    } else {
        int idx = (b - WCONV_BLKS) * 256 + threadIdx.x;
        if (idx < ZERO_INT4S) cnt4[idx] = make_int4(0, 0, 0, 0);
    }
}

// ---------------------------------------------------------------------------
// fill: 4 edges per thread. 3 coalesced int4 loads (48B), then 4 INDEPENDENT
// atomic->store chains in flight (the r9 version had exactly one chain per
// thread — pure latency serialization).
// ---------------------------------------------------------------------------
__global__ __launch_bounds__(256) void fill(const int* __restrict__ edges,
                                            int* __restrict__ cnt,
                                            unsigned* __restrict__ buckets,
                                            int* __restrict__ ocount,
                                            uint2* __restrict__ obuf)
{
    int t4 = blockIdx.x * 256 + threadIdx.x;
    if (t4 >= FILL_THREADS) return;
    const int4* ei = (const int4*)edges + (size_t)t4 * 3;
    int4 a = ei[0];
    int4 b = ei[1];
    int4 cc = ei[2];
    // layout: [s0 r0 d0 s1][r1 d1 s2 r2][d2 s3 r3 d3]
    int d0 = a.z,  d1 = b.y,  d2 = cc.x, d3 = cc.w;
    unsigned p0 = (unsigned)a.x  | ((unsigned)a.y  << 16);
    unsigned p1 = (unsigned)a.w  | ((unsigned)b.x  << 16);
    unsigned p2 = (unsigned)b.z  | ((unsigned)b.w  << 16);
    unsigned p3 = (unsigned)cc.y | ((unsigned)cc.z << 16);

    int q0 = atomicAdd(cnt + d0, 1);
    int q1 = atomicAdd(cnt + d1, 1);
    int q2 = atomicAdd(cnt + d2, 1);
    int q3 = atomicAdd(cnt + d3, 1);

    if (q0 < CAP) buckets[(size_t)d0 * CAP + q0] = p0;
    else { int o = atomicAdd(ocount, 1); if (o < OCAP) obuf[o] = make_uint2((unsigned)d0, p0); }
    if (q1 < CAP) buckets[(size_t)d1 * CAP + q1] = p1;
    else { int o = atomicAdd(ocount, 1); if (o < OCAP) obuf[o] = make_uint2((unsigned)d1, p1); }
    if (q2 < CAP) buckets[(size_t)d2 * CAP + q2] = p2;
    else { int o = atomicAdd(ocount, 1); if (o < OCAP) obuf[o] = make_uint2((unsigned)d2, p2); }
    if (q3 < CAP) buckets[(size_t)d3 * CAP + q3] = p3;
    else { int o = atomicAdd(ocount, 1); if (o < OCAP) obuf[o] = make_uint2((unsigned)d3, p3); }
}

// ---------------------------------------------------------------------------
// ts_kernel: fused two-phase GEMM, ONE aliased LDS buffer (34.8 KB):
//   [stage Wn^T] -> MFMA T (accs in VGPR) -> [T tile] -> store T
//   [stage (I+Ws)^T] -> MFMA Sp -> [Sp tile] -> store Sp
// 4 blocks/CU (16 waves/CU).
// ---------------------------------------------------------------------------
__global__ __launch_bounds__(256, 4) void ts_kernel(
    const float* __restrict__ nodes, const float* __restrict__ rels,
    const unsigned short* __restrict__ btn, const unsigned short* __restrict__ bts,
    unsigned short* __restrict__ T, unsigned short* __restrict__ U,
    float* __restrict__ Sp)
{
    __shared__ __align__(16) char ldsRaw[DIM * BP * 2];   // 34816 B
    unsigned short* ldsB = (unsigned short*)ldsRaw;
    unsigned short* ldsT = (unsigned short*)ldsRaw;       // aliased views
    float*          ldsS = (float*)ldsRaw;

    int blk = blockIdx.x;
    bool isRel = blk >= NODE_BLKS;
    const float* A = isRel ? rels : nodes;
    int nrows = isRel ? NRELS : NNODES;
    int rowbase = (isRel ? (blk - NODE_BLKS) : blk) * 64;

    int t  = threadIdx.x;
    int wv = t >> 6;
    int l  = t & 63;
    int r0 = rowbase + wv * 16;
    int m  = l & 15;
    int kg = l >> 4;
    int arow  = r0 + m;
    int arowc = arow < nrows ? arow : nrows - 1;

    // A fragments, loaded/converted ONCE for both phases
    s8f afrag[4];
    #pragma unroll
    for (int ks = 0; ks < 4; ++ks) {
        const float* p = A + (size_t)arowc * DIM + ks * 32 + kg * 8;
        float4 x = *(const float4*)p;
        float4 y = *(const float4*)(p + 4);
        s8f a;
        a[0] = (short)f2bf(x.x); a[1] = (short)f2bf(x.y);
        a[2] = (short)f2bf(x.z); a[3] = (short)f2bf(x.w);
        a[4] = (short)f2bf(y.x); a[5] = (short)f2bf(y.y);
        a[6] = (short)f2bf(y.z); a[7] = (short)f2bf(y.w);
        afrag[ks] = a;
    }

    // ---- phase 1: T/U = A @ Wn ----
    #pragma unroll
    for (int i = 0; i < 8; ++i) {                  // stage Wn^T
        int idx = t + i * 256;
        int col = idx >> 4, slot = idx & 15;
        *(uint4*)(ldsB + (size_t)col * BP + slot * 8) =
            *(const uint4*)(btn + (size_t)col * DIM + slot * 8);
    }
    __syncthreads();

    f4 acc[8];
    #pragma unroll
    for (int ct = 0; ct < 8; ++ct) {
        int col = ct * 16 + m;
        const unsigned short* bp = ldsB + (size_t)col * BP + kg * 8;
        f4 a = {0.f, 0.f, 0.f, 0.f};
        #pragma unroll
        for (int ks = 0; ks < 4; ++ks)
            a = __builtin_amdgcn_mfma_f32_16x16x32_bf16(afrag[ks], *(const s8f*)(bp + ks * 32), a, 0, 0, 0);
        acc[ct] = a;
    }
    __syncthreads();   // all ldsB reads done; safe to overwrite as ldsT

    #pragma unroll
    for (int ct = 0; ct < 8; ++ct)
        #pragma unroll
        for (int r = 0; r < 4; ++r)
            ldsT[((size_t)wv * 16 + kg * 4 + r) * TP + ct * 16 + m] = f2bf(acc[ct][r]);
    __syncthreads();

    unsigned short* Tout = isRel ? U : T;
    #pragma unroll
    for (int p = 0; p < 4; ++p) {
        int row = p * 4 + kg;
        int rg  = r0 + row;
        if (rg < nrows)
            *(uint4*)(Tout + (size_t)rg * DIM + m * 8) =
                *(const uint4*)&ldsT[((size_t)wv * 16 + row) * TP + m * 8];
    }
    if (isRel) return;   // whole block is rel -> uniform exit

    __syncthreads();   // ldsT reads done; safe to restage

    // ---- phase 2: Sp = A @ (I+Ws) ----
    #pragma unroll
    for (int i = 0; i < 8; ++i) {                  // stage (I+Ws)^T
        int idx = t + i * 256;
        int col = idx >> 4, slot = idx & 15;
        *(uint4*)(ldsB + (size_t)col * BP + slot * 8) =
            *(const uint4*)(bts + (size_t)col * DIM + slot * 8);
    }
    __syncthreads();

    #pragma unroll
    for (int ct = 0; ct < 8; ++ct) {
        int col = ct * 16 + m;
        const unsigned short* bp = ldsB + (size_t)col * BP + kg * 8;
        f4 a = {0.f, 0.f, 0.f, 0.f};
        #pragma unroll
        for (int ks = 0; ks < 4; ++ks)
            a = __builtin_amdgcn_mfma_f32_16x16x32_bf16(afrag[ks], *(const s8f*)(bp + ks * 32), a, 0, 0, 0);
        acc[ct] = a;
    }
    __syncthreads();   // ldsB reads done; overwrite as ldsS

    #pragma unroll
    for (int ct = 0; ct < 8; ++ct)
        #pragma unroll
        for (int r = 0; r < 4; ++r)
            ldsS[((size_t)wv * 16 + kg * 4 + r) * SP + ct * 16 + m] = acc[ct][r];
    __syncthreads();

    #pragma unroll
    for (int p = 0; p < 4; ++p) {
        int row = p * 4 + kg;
        int rg  = r0 + row;
        if (rg < NNODES) {
            float* orow = Sp + (size_t)rg * DIM;
            #pragma unroll
            for (int j = 0; j < 2; ++j) {
                int c0 = m * 4 + j * 64;
                *(float4*)(orow + c0) =
                    *(const float4*)&ldsS[((size_t)wv * 16 + row) * SP + c0];
            }
        }
    }
}

// ---------------------------------------------------------------------------
// gather: full wave per node. Lane l prefetches bucket entry l (one coalesced
// load). Batch loop trip count is WAVE-UNIFORM; all __shfl broadcasts execute
// at full-wave activity; only guarded row-loads diverge in the tail batch.
// Sp row read hoisted above the loop (independent -> off the critical tail).
// ---------------------------------------------------------------------------
#define ACC1(b) { \
    uint2 tt = *(const uint2*)(T + (size_t)((b) & 0xFFFFu) * DIM + c * 4); \
    uint2 uu = *(const uint2*)(U + (size_t)((b) >> 16)     * DIM + c * 4); \
    acc.x += bflo(tt.x) + bflo(uu.x); acc.y += bfhi(tt.x) + bfhi(uu.x); \
    acc.z += bflo(tt.y) + bflo(uu.y); acc.w += bfhi(tt.y) + bfhi(uu.y); }

__global__ __launch_bounds__(256) void gather(
    const unsigned short* __restrict__ T, const unsigned short* __restrict__ U,
    const int* __restrict__ cnt, const unsigned* __restrict__ buckets,
    const int* __restrict__ ocount, const uint2* __restrict__ obuf,
    const float* __restrict__ nodes, const float* __restrict__ wse,
    float* __restrict__ outp)
{
    int tid = blockIdx.x * 256 + threadIdx.x;
    int n = tid >> 6;
    if (n >= NNODES) return;
    int l = threadIdx.x & 63;
    int half = l >> 5;
    int c = l & 31;

    int deg = cnt[n];    // wave-uniform

    if (deg == 0) {
        // rare (~6e-6 per node): out = h + h @ Wse, straight f32 matvec
        if (half == 0) {
            float s0 = 0, s1 = 0, s2 = 0, s3 = 0;
            for (int k = 0; k < DIM; ++k) {
                float hk = nodes[(size_t)n * DIM + k];
                const float* wr = wse + (size_t)k * DIM + c * 4;
                s0 += hk * wr[0]; s1 += hk * wr[1];
                s2 += hk * wr[2]; s3 += hk * wr[3];
            }
            float4 hv = *(const float4*)(nodes + (size_t)n * DIM + c * 4);
            float4 o = { hv.x + s0, hv.y + s1, hv.z + s2, hv.w + s3 };
            *(float4*)(outp + (size_t)n * DIM + c * 4) = o;
        }
        return;
    }

    int degc = deg < CAP ? deg : CAP;   // wave-uniform
    // lane-parallel bucket prefetch + early Sp row read (independent loads)
    unsigned myent = (l < degc) ? buckets[(size_t)n * CAP + l] : 0u;
    float4 sp = make_float4(0.f, 0.f, 0.f, 0.f);
    if (half == 0) sp = *(const float4*)(outp + (size_t)n * DIM + c * 4);

    float4 acc = make_float4(0.f, 0.f, 0.f, 0.f);
    for (int jb = 0; jb < degc; jb += 8) {      // UNIFORM loop condition
        int j0 = jb + half;
        // shfls at full-wave activity (no divergence here)
        unsigned b0 = __shfl(myent, j0,     64);
        unsigned b1 = __shfl(myent, j0 + 2, 64);
        unsigned b2 = __shfl(myent, j0 + 4, 64);
        unsigned b3 = __shfl(myent, j0 + 6, 64);
        if (jb + 8 <= degc) {                   // UNIFORM: full batch
            ACC1(b0); ACC1(b1); ACC1(b2); ACC1(b3);
        } else {                                // UNIFORM: tail batch
            if (j0     < degc) ACC1(b0);        // divergent guards: loads only
            if (j0 + 2 < degc) ACC1(b1);
            if (j0 + 4 < degc) ACC1(b2);
            if (j0 + 6 < degc) ACC1(b3);
        }
    }

    if (deg > CAP) {                            // wave-uniform, ~never taken
        int oc = *ocount;
        if (oc > OCAP) oc = OCAP;
        for (int k = 0; k < oc; ++k) {
            uint2 e = obuf[k];
            if ((int)e.x == n && (k & 1) == half) {
                unsigned b0 = e.y;
                ACC1(b0);
            }
        }
    }

    acc.x += __shfl_xor(acc.x, 32, 64);
    acc.y += __shfl_xor(acc.y, 32, 64);
    acc.z += __shfl_xor(acc.z, 32, 64);
    acc.w += __shfl_xor(acc.w, 32, 64);

    if (half == 0) {
        float inv = 1.0f / (float)deg;
        float4 o = { sp.x + acc.x * inv, sp.y + acc.y * inv,
                     sp.z + acc.z * inv, sp.w + acc.w * inv };
        *(float4*)(outp + (size_t)n * DIM + c * 4) = o;
    }
}

// ---------------------------------------------------------------------------
extern "C" void kernel_launch(void* const* d_in, const int* in_sizes, int n_in,
                              void* d_out, int out_size, void* d_ws, size_t ws_size,
                              hipStream_t stream)
{
    const float* nodes = (const float*)d_in[0];
    const float* rels  = (const float*)d_in[1];
    const int*   edges = (const int*)d_in[2];
    const float* wn    = (const float*)d_in[3];
    const float* wsf   = (const float*)d_in[4];
    const float* wse   = (const float*)d_in[5];
    float* out = (float*)d_out;

    char* ws = (char*)d_ws;
    int*            cnt     = (int*)(ws + OFF_CNT_B);
    int*            ocount  = (int*)(ws + OFF_OCNT_B);
    uint2*          obuf    = (uint2*)(ws + OFF_OBUF_B);
    unsigned*       buckets = (unsigned*)(ws + OFF_BKT_B);
    unsigned short* btn     = (unsigned short*)(ws + OFF_BTN_B);
    unsigned short* bts     = (unsigned short*)(ws + OFF_BTS_B);
    unsigned short* T       = (unsigned short*)(ws + OFF_T_B);
    unsigned short* U       = (unsigned short*)(ws + OFF_U_B);

    prep<<<PREP_BLKS, 256, 0, stream>>>(wn, wsf, btn, bts, (int4*)cnt);

    fill<<<FILL_BLKS, 256, 0, stream>>>(edges, cnt, buckets, ocount, obuf);

    ts_kernel<<<TS_BLKS, 256, 0, stream>>>(nodes, rels, btn, bts, T, U, out);

    int gb = (NNODES * 64 + 255) / 256;
    gather<<<gb, 256, 0, stream>>>(T, U, cnt, buckets, ocount, obuf, nodes, wse, out);
}

// Round 13
// 93.285 us; speedup vs baseline: 1.1569x; 1.0330x over previous
//
#include <hip/hip_runtime.h>

// URGCN layer, MI355X — round 13.
// r12 post-mortem: fill's 4-edge ILP gained ~nothing -> fill is bound by
// scattered-store TRANSACTION RATE (600k lone 4B stores ~ 64B granule each),
// not per-thread latency. Fixing that needs a coalescing radix sort (held in
// reserve). This round: gather processes TWO nodes per wave with a merged
// batch loop -> 16 loads in flight, prologue chains overlapped, both halves
// write in the epilogue. All shfls remain at full-wave activity.
//
// Algebra: msg_agg = (Σ_e T[src] + u[rel]) / deg, T = h@Wn (bf16 MFMA),
//          u = rel@Wn.  out = Sp + msg_agg, Sp = h@(I+Wself) (f32, in d_out).

constexpr int NNODES = 50000;
constexpr int NEDGES = 600000;
constexpr int NRELS  = 500;
constexpr int DIM    = 128;
constexpr int CAP    = 48;      // bucket capacity per node
constexpr int OCAP   = 8192;    // overflow list capacity

constexpr int NODE_BLKS = (NNODES + 63) / 64;   // 782
constexpr int REL_BLKS  = (NRELS  + 63) / 64;   // 8
constexpr int TS_BLKS   = NODE_BLKS + REL_BLKS; // 790

constexpr int BP = 136;   // LDS B row pitch (shorts); 272B -> banks spread
constexpr int TP = 136;   // LDS T tile pitch (shorts)
constexpr int SP = 132;   // LDS S tile pitch (floats)

// prep geometry: zero cnt[50000] + ocount (50004 ints -> 12501 int4)
constexpr int WCONV_BLKS = (DIM * DIM + 255) / 256;            // 64
constexpr int ZERO_INT4S = 12501;
constexpr int ZERO_BLKS  = (ZERO_INT4S + 255) / 256;           // 49
constexpr int PREP_BLKS  = WCONV_BLKS + ZERO_BLKS;             // 113

// fill geometry: 4 edges/thread, 600000/4 = 150000 threads
constexpr int FILL_THREADS = NEDGES / 4;                       // 150000
constexpr int FILL_BLKS    = (FILL_THREADS + 255) / 256;       // 586

// gather geometry: 2 nodes per wave, 25000 waves
constexpr int GATHER_BLKS  = (NNODES / 2 * 64) / 256;          // 6250

// ---------------- workspace layout (bytes) ----------------
constexpr size_t OFF_CNT_B  = 0;         // int[50000]
constexpr size_t OFF_OCNT_B = 200000;    // int ocount (zeroed with cnt)
constexpr size_t OFF_OBUF_B = 204800;    // uint2[8192]
constexpr size_t OFF_BKT_B  = 270336;    // uint[50000*48] = 9.6 MB
constexpr size_t OFF_BTN_B  = OFF_BKT_B + (size_t)NNODES * CAP * 4;  // Wn^T bf16
constexpr size_t OFF_BTS_B  = OFF_BTN_B + 32768;                     // (I+Ws)^T bf16
constexpr size_t OFF_T_B    = OFF_BTS_B + 32768;                     // ushort[50000*128]
constexpr size_t OFF_U_B    = OFF_T_B + (size_t)NNODES * DIM * 2;    // ushort[500*128]

typedef short s8f __attribute__((ext_vector_type(8)));   // 8 bf16 (4 VGPR)
typedef float f4  __attribute__((ext_vector_type(4)));   // MFMA acc

static __device__ __forceinline__ unsigned short f2bf(float f) {
    unsigned u = __builtin_bit_cast(unsigned, f);
    u += 0x7FFFu + ((u >> 16) & 1u);        // round-to-nearest-even
    return (unsigned short)(u >> 16);
}
static __device__ __forceinline__ float bflo(unsigned v) {
    return __builtin_bit_cast(float, v << 16);
}
static __device__ __forceinline__ float bfhi(unsigned v) {
    return __builtin_bit_cast(float, v & 0xFFFF0000u);
}

// ---------------------------------------------------------------------------
// prep: blocks [0,64) convert weights; blocks [64,113) zero cnt+ocount.
__global__ __launch_bounds__(256) void prep(const float* __restrict__ wn,
                                            const float* __restrict__ wsf,
                                            unsigned short* __restrict__ btn,
                                            unsigned short* __restrict__ bts,
                                            int4* __restrict__ cnt4)
{
    int b = blockIdx.x;
    if (b < WCONV_BLKS) {
        int idx = b * 256 + threadIdx.x;
        int k = idx >> 7, j = idx & 127;
        btn[(size_t)j * DIM + k] = f2bf(wn[idx]);                         // Wn^T
        bts[(size_t)j * DIM + k] = f2bf(wsf[idx] + (k == j ? 1.f : 0.f)); // (I+Ws)^T
    } else {
        int idx = (b - WCONV_BLKS) * 256 + threadIdx.x;
        if (idx < ZERO_INT4S) cnt4[idx] = make_int4(0, 0, 0, 0);
    }
}

// ---------------------------------------------------------------------------
// fill: 4 edges per thread, 3 coalesced int4 loads, 4 atomic->store chains.
__global__ __launch_bounds__(256) void fill(const int* __restrict__ edges,
                                            int* __restrict__ cnt,
                                            unsigned* __restrict__ buckets,
                                            int* __restrict__ ocount,
                                            uint2* __restrict__ obuf)
{
    int t4 = blockIdx.x * 256 + threadIdx.x;
    if (t4 >= FILL_THREADS) return;
    const int4* ei = (const int4*)edges + (size_t)t4 * 3;
    int4 a = ei[0];
    int4 b = ei[1];
    int4 cc = ei[2];
    // layout: [s0 r0 d0 s1][r1 d1 s2 r2][d2 s3 r3 d3]
    int d0 = a.z,  d1 = b.y,  d2 = cc.x, d3 = cc.w;
    unsigned p0 = (unsigned)a.x  | ((unsigned)a.y  << 16);
    unsigned p1 = (unsigned)a.w  | ((unsigned)b.x  << 16);
    unsigned p2 = (unsigned)b.z  | ((unsigned)b.w  << 16);
    unsigned p3 = (unsigned)cc.y | ((unsigned)cc.z << 16);

    int q0 = atomicAdd(cnt + d0, 1);
    int q1 = atomicAdd(cnt + d1, 1);
    int q2 = atomicAdd(cnt + d2, 1);
    int q3 = atomicAdd(cnt + d3, 1);

    if (q0 < CAP) buckets[(size_t)d0 * CAP + q0] = p0;
    else { int o = atomicAdd(ocount, 1); if (o < OCAP) obuf[o] = make_uint2((unsigned)d0, p0); }
    if (q1 < CAP) buckets[(size_t)d1 * CAP + q1] = p1;
    else { int o = atomicAdd(ocount, 1); if (o < OCAP) obuf[o] = make_uint2((unsigned)d1, p1); }
    if (q2 < CAP) buckets[(size_t)d2 * CAP + q2] = p2;
    else { int o = atomicAdd(ocount, 1); if (o < OCAP) obuf[o] = make_uint2((unsigned)d2, p2); }
    if (q3 < CAP) buckets[(size_t)d3 * CAP + q3] = p3;
    else { int o = atomicAdd(ocount, 1); if (o < OCAP) obuf[o] = make_uint2((unsigned)d3, p3); }
}

// ---------------------------------------------------------------------------
// ts_kernel: fused two-phase GEMM, ONE aliased LDS buffer (34.8 KB), 4 blk/CU.
// ---------------------------------------------------------------------------
__global__ __launch_bounds__(256, 4) void ts_kernel(
    const float* __restrict__ nodes, const float* __restrict__ rels,
    const unsigned short* __restrict__ btn, const unsigned short* __restrict__ bts,
    unsigned short* __restrict__ T, unsigned short* __restrict__ U,
    float* __restrict__ Sp)
{
    __shared__ __align__(16) char ldsRaw[DIM * BP * 2];   // 34816 B
    unsigned short* ldsB = (unsigned short*)ldsRaw;
    unsigned short* ldsT = (unsigned short*)ldsRaw;       // aliased views
    float*          ldsS = (float*)ldsRaw;

    int blk = blockIdx.x;
    bool isRel = blk >= NODE_BLKS;
    const float* A = isRel ? rels : nodes;
    int nrows = isRel ? NRELS : NNODES;
    int rowbase = (isRel ? (blk - NODE_BLKS) : blk) * 64;

    int t  = threadIdx.x;
    int wv = t >> 6;
    int l  = t & 63;
    int r0 = rowbase + wv * 16;
    int m  = l & 15;
    int kg = l >> 4;
    int arow  = r0 + m;
    int arowc = arow < nrows ? arow : nrows - 1;

    s8f afrag[4];
    #pragma unroll
    for (int ks = 0; ks < 4; ++ks) {
        const float* p = A + (size_t)arowc * DIM + ks * 32 + kg * 8;
        float4 x = *(const float4*)p;
        float4 y = *(const float4*)(p + 4);
        s8f a;
        a[0] = (short)f2bf(x.x); a[1] = (short)f2bf(x.y);
        a[2] = (short)f2bf(x.z); a[3] = (short)f2bf(x.w);
        a[4] = (short)f2bf(y.x); a[5] = (short)f2bf(y.y);
        a[6] = (short)f2bf(y.z); a[7] = (short)f2bf(y.w);
        afrag[ks] = a;
    }

    // ---- phase 1: T/U = A @ Wn ----
    #pragma unroll
    for (int i = 0; i < 8; ++i) {                  // stage Wn^T
        int idx = t + i * 256;
        int col = idx >> 4, slot = idx & 15;
        *(uint4*)(ldsB + (size_t)col * BP + slot * 8) =
            *(const uint4*)(btn + (size_t)col * DIM + slot * 8);
    }
    __syncthreads();

    f4 acc[8];
    #pragma unroll
    for (int ct = 0; ct < 8; ++ct) {
        int col = ct * 16 + m;
        const unsigned short* bp = ldsB + (size_t)col * BP + kg * 8;
        f4 a = {0.f, 0.f, 0.f, 0.f};
        #pragma unroll
        for (int ks = 0; ks < 4; ++ks)
            a = __builtin_amdgcn_mfma_f32_16x16x32_bf16(afrag[ks], *(const s8f*)(bp + ks * 32), a, 0, 0, 0);
        acc[ct] = a;
    }
    __syncthreads();   // all ldsB reads done; safe to overwrite as ldsT

    #pragma unroll
    for (int ct = 0; ct < 8; ++ct)
        #pragma unroll
        for (int r = 0; r < 4; ++r)
            ldsT[((size_t)wv * 16 + kg * 4 + r) * TP + ct * 16 + m] = f2bf(acc[ct][r]);
    __syncthreads();

    unsigned short* Tout = isRel ? U : T;
    #pragma unroll
    for (int p = 0; p < 4; ++p) {
        int row = p * 4 + kg;
        int rg  = r0 + row;
        if (rg < nrows)
            *(uint4*)(Tout + (size_t)rg * DIM + m * 8) =
                *(const uint4*)&ldsT[((size_t)wv * 16 + row) * TP + m * 8];
    }
    if (isRel) return;   // whole block is rel -> uniform exit

    __syncthreads();   // ldsT reads done; safe to restage

    // ---- phase 2: Sp = A @ (I+Ws) ----
    #pragma unroll
    for (int i = 0; i < 8; ++i) {                  // stage (I+Ws)^T
        int idx = t + i * 256;
        int col = idx >> 4, slot = idx & 15;
        *(uint4*)(ldsB + (size_t)col * BP + slot * 8) =
            *(const uint4*)(bts + (size_t)col * DIM + slot * 8);
    }
    __syncthreads();

    #pragma unroll
    for (int ct = 0; ct < 8; ++ct) {
        int col = ct * 16 + m;
        const unsigned short* bp = ldsB + (size_t)col * BP + kg * 8;
        f4 a = {0.f, 0.f, 0.f, 0.f};
        #pragma unroll
        for (int ks = 0; ks < 4; ++ks)
            a = __builtin_amdgcn_mfma_f32_16x16x32_bf16(afrag[ks], *(const s8f*)(bp + ks * 32), a, 0, 0, 0);
        acc[ct] = a;
    }
    __syncthreads();   // ldsB reads done; overwrite as ldsS

    #pragma unroll
    for (int ct = 0; ct < 8; ++ct)
        #pragma unroll
        for (int r = 0; r < 4; ++r)
            ldsS[((size_t)wv * 16 + kg * 4 + r) * SP + ct * 16 + m] = acc[ct][r];
    __syncthreads();

    #pragma unroll
    for (int p = 0; p < 4; ++p) {
        int row = p * 4 + kg;
        int rg  = r0 + row;
        if (rg < NNODES) {
            float* orow = Sp + (size_t)rg * DIM;
            #pragma unroll
            for (int j = 0; j < 2; ++j) {
                int c0 = m * 4 + j * 64;
                *(float4*)(orow + c0) =
                    *(const float4*)&ldsS[((size_t)wv * 16 + row) * SP + c0];
            }
        }
    }
}

// ---------------------------------------------------------------------------
// gather: TWO nodes per wave. Prologues (cnt, bucket row, Sp row) for both
// nodes issue as independent loads; merged batch loop keeps 16 T/U loads in
// flight. All shfls at full-wave activity (per-node guards are wave-uniform).
// Epilogue: half 0 writes node0's row, half 1 writes node1's row.
// ---------------------------------------------------------------------------
#define ACCP(A, b) { \
    uint2 tt = *(const uint2*)(T + (size_t)((b) & 0xFFFFu) * DIM + c * 4); \
    uint2 uu = *(const uint2*)(U + (size_t)((b) >> 16)     * DIM + c * 4); \
    A.x += bflo(tt.x) + bflo(uu.x); A.y += bfhi(tt.x) + bfhi(uu.x); \
    A.z += bflo(tt.y) + bflo(uu.y); A.w += bfhi(tt.y) + bfhi(uu.y); }

#define BATCH(my, degc, A) \
    if (jb < degc) { \
        unsigned b0 = __shfl(my, j0,     64); \
        unsigned b1 = __shfl(my, j0 + 2, 64); \
        unsigned b2 = __shfl(my, j0 + 4, 64); \
        unsigned b3 = __shfl(my, j0 + 6, 64); \
        if (jb + 8 <= degc) { ACCP(A, b0); ACCP(A, b1); ACCP(A, b2); ACCP(A, b3); } \
        else { \
            if (j0     < degc) ACCP(A, b0); \
            if (j0 + 2 < degc) ACCP(A, b1); \
            if (j0 + 4 < degc) ACCP(A, b2); \
            if (j0 + 6 < degc) ACCP(A, b3); } }

__global__ __launch_bounds__(256) void gather(
    const unsigned short* __restrict__ T, const unsigned short* __restrict__ U,
    const int* __restrict__ cnt, const unsigned* __restrict__ buckets,
    const int* __restrict__ ocount, const uint2* __restrict__ obuf,
    const float* __restrict__ nodes, const float* __restrict__ wse,
    float* __restrict__ outp)
{
    int wid = (blockIdx.x * 256 + threadIdx.x) >> 6;
    if (wid >= NNODES / 2) return;
    int n0 = wid * 2;
    int n1 = n0 + 1;
    int l = threadIdx.x & 63;
    int half = l >> 5;
    int c = l & 31;

    int deg0 = cnt[n0];                  // wave-uniform
    int deg1 = cnt[n1];                  // wave-uniform
    int degc0 = deg0 < CAP ? deg0 : CAP;
    int degc1 = deg1 < CAP ? deg1 : CAP;

    // independent prologue loads: both bucket rows + this half's Sp row
    unsigned my0 = (l < degc0) ? buckets[(size_t)n0 * CAP + l] : 0u;
    unsigned my1 = (l < degc1) ? buckets[(size_t)n1 * CAP + l] : 0u;
    int nm = half ? n1 : n0;
    float4 spm = *(const float4*)(outp + (size_t)nm * DIM + c * 4);

    float4 acc0 = make_float4(0.f, 0.f, 0.f, 0.f);
    float4 acc1 = make_float4(0.f, 0.f, 0.f, 0.f);
    int maxd = degc0 > degc1 ? degc0 : degc1;
    for (int jb = 0; jb < maxd; jb += 8) {   // wave-uniform condition
        int j0 = jb + half;
        BATCH(my0, degc0, acc0);             // wave-uniform guard
        BATCH(my1, degc1, acc1);             // independent -> overlapped loads
    }

    if ((deg0 > CAP) || (deg1 > CAP)) {      // wave-uniform, ~never taken
        int oc = *ocount;
        if (oc > OCAP) oc = OCAP;
        for (int k = 0; k < oc; ++k) {
            uint2 e = obuf[k];
            if ((int)e.x == n0 && (k & 1) == half) ACCP(acc0, e.y);
            if ((int)e.x == n1 && (k & 1) == half) ACCP(acc1, e.y);
        }
    }

    // cross-half reductions at full-wave activity
    acc0.x += __shfl_xor(acc0.x, 32, 64);
    acc0.y += __shfl_xor(acc0.y, 32, 64);
    acc0.z += __shfl_xor(acc0.z, 32, 64);
    acc0.w += __shfl_xor(acc0.w, 32, 64);
    acc1.x += __shfl_xor(acc1.x, 32, 64);
    acc1.y += __shfl_xor(acc1.y, 32, 64);
    acc1.z += __shfl_xor(acc1.z, 32, 64);
    acc1.w += __shfl_xor(acc1.w, 32, 64);

    // epilogue: each half writes its own node's row (divergent stores only)
    float4 am = half ? acc1 : acc0;
    int dm = half ? deg1 : deg0;
    if (dm > 0) {
        float inv = 1.0f / (float)dm;
        float4 o = { spm.x + am.x * inv, spm.y + am.y * inv,
                     spm.z + am.z * inv, spm.w + am.w * inv };
        *(float4*)(outp + (size_t)nm * DIM + c * 4) = o;
    }

    // rare deg==0 fallback: out = h + h @ Wse (wave-uniform branches)
    if (deg0 == 0 && half == 0) {
        float s0 = 0, s1 = 0, s2 = 0, s3 = 0;
        for (int k = 0; k < DIM; ++k) {
            float hk = nodes[(size_t)n0 * DIM + k];
            const float* wr = wse + (size_t)k * DIM + c * 4;
            s0 += hk * wr[0]; s1 += hk * wr[1];
            s2 += hk * wr[2]; s3 += hk * wr[3];
        }
        float4 hv = *(const float4*)(nodes + (size_t)n0 * DIM + c * 4);
        float4 o = { hv.x + s0, hv.y + s1, hv.z + s2, hv.w + s3 };
        *(float4*)(outp + (size_t)n0 * DIM + c * 4) = o;
    }
    if (deg1 == 0 && half == 1) {
        float s0 = 0, s1 = 0, s2 = 0, s3 = 0;
        for (int k = 0; k < DIM; ++k) {
            float hk = nodes[(size_t)n1 * DIM + k];
            const float* wr = wse + (size_t)k * DIM + c * 4;
            s0 += hk * wr[0]; s1 += hk * wr[1];
            s2 += hk * wr[2]; s3 += hk * wr[3];
        }
        float4 hv = *(const float4*)(nodes + (size_t)n1 * DIM + c * 4);
        float4 o = { hv.x + s0, hv.y + s1, hv.z + s2, hv.w + s3 };
        *(float4*)(outp + (size_t)n1 * DIM + c * 4) = o;
    }
}

// ---------------------------------------------------------------------------
extern "C" void kernel_launch(void* const* d_in, const int* in_sizes, int n_in,
                              void* d_out, int out_size, void* d_ws, size_t ws_size,
                              hipStream_t stream)
{
    const float* nodes = (const float*)d_in[0];
    const float* rels  = (const float*)d_in[1];
    const int*   edges = (const int*)d_in[2];
    const float* wn    = (const float*)d_in[3];
    const float* wsf   = (const float*)d_in[4];
    const float* wse   = (const float*)d_in[5];
    float* out = (float*)d_out;

    char* ws = (char*)d_ws;
    int*            cnt     = (int*)(ws + OFF_CNT_B);
    int*            ocount  = (int*)(ws + OFF_OCNT_B);
    uint2*          obuf    = (uint2*)(ws + OFF_OBUF_B);
    unsigned*       buckets = (unsigned*)(ws + OFF_BKT_B);
    unsigned short* btn     = (unsigned short*)(ws + OFF_BTN_B);
    unsigned short* bts     = (unsigned short*)(ws + OFF_BTS_B);
    unsigned short* T       = (unsigned short*)(ws + OFF_T_B);
    unsigned short* U       = (unsigned short*)(ws + OFF_U_B);

    prep<<<PREP_BLKS, 256, 0, stream>>>(wn, wsf, btn, bts, (int4*)cnt);

    fill<<<FILL_BLKS, 256, 0, stream>>>(edges, cnt, buckets, ocount, obuf);

    ts_kernel<<<TS_BLKS, 256, 0, stream>>>(nodes, rels, btn, bts, T, U, out);

    int gb = GATHER_BLKS;
    gather<<<gb, 256, 0, stream>>>(T, U, cnt, buckets, ocount, obuf, nodes, wse, out);
}

// Round 14
// 92.855 us; speedup vs baseline: 1.1622x; 1.0046x over previous
//
#include <hip/hip_runtime.h>

// URGCN layer, MI355X — round 14.
// r13 post-mortem: fill (~39us) and gather (~40us) are both ILP-insensitive ->
// throughput-bound. Fill arithmetic: 600k atomics over 50k counters = 16
// counters/line, 192 atomics/line -> same-line L2 RMW serialization (14 G/s
// observed vs 74 G/s when spread, r0). Fix: pad counters to ONE PER 64B LINE
// (cnt[dst*16], 3.2MB). Everything else unchanged from r13.
//
// Algebra: msg_agg = (Σ_e T[src] + u[rel]) / deg, T = h@Wn (bf16 MFMA),
//          u = rel@Wn.  out = Sp + msg_agg, Sp = h@(I+Wself) (f32, in d_out).

constexpr int NNODES = 50000;
constexpr int NEDGES = 600000;
constexpr int NRELS  = 500;
constexpr int DIM    = 128;
constexpr int CAP    = 48;      // bucket capacity per node
constexpr int OCAP   = 8192;    // overflow list capacity
constexpr int CSTR   = 16;      // cnt stride in ints: one counter per 64B line

constexpr int NODE_BLKS = (NNODES + 63) / 64;   // 782
constexpr int REL_BLKS  = (NRELS  + 63) / 64;   // 8
constexpr int TS_BLKS   = NODE_BLKS + REL_BLKS; // 790

constexpr int BP = 136;   // LDS B row pitch (shorts); 272B -> banks spread
constexpr int TP = 136;   // LDS T tile pitch (shorts)
constexpr int SP = 132;   // LDS S tile pitch (floats)

// prep geometry: zero cnt[50000*16] + ocount  -> 200001 int4
constexpr int WCONV_BLKS = (DIM * DIM + 255) / 256;            // 64
constexpr int ZERO_INT4S = 200001;
constexpr int ZERO_BLKS  = (ZERO_INT4S + 255) / 256;           // 782
constexpr int PREP_BLKS  = WCONV_BLKS + ZERO_BLKS;             // 846

// fill geometry: 4 edges/thread, 600000/4 = 150000 threads
constexpr int FILL_THREADS = NEDGES / 4;                       // 150000
constexpr int FILL_BLKS    = (FILL_THREADS + 255) / 256;       // 586

// gather geometry: 2 nodes per wave, 25000 waves
constexpr int GATHER_BLKS  = (NNODES / 2 * 64) / 256;          // 6250

// ---------------- workspace layout (bytes), ~25.9 MB ----------------
constexpr size_t OFF_CNT_B  = 0;          // int[50000*16] padded counters (3.2MB)
constexpr size_t OFF_OCNT_B = 3200000;    // int ocount (zeroed with cnt)
constexpr size_t OFF_OBUF_B = 3204800;    // uint2[8192]
constexpr size_t OFF_BKT_B  = 3270336;    // uint[50000*48] = 9.6 MB
constexpr size_t OFF_BTN_B  = OFF_BKT_B + (size_t)NNODES * CAP * 4;  // Wn^T bf16
constexpr size_t OFF_BTS_B  = OFF_BTN_B + 32768;                     // (I+Ws)^T bf16
constexpr size_t OFF_T_B    = OFF_BTS_B + 32768;                     // ushort[50000*128]
constexpr size_t OFF_U_B    = OFF_T_B + (size_t)NNODES * DIM * 2;    // ushort[500*128]

typedef short s8f __attribute__((ext_vector_type(8)));   // 8 bf16 (4 VGPR)
typedef float f4  __attribute__((ext_vector_type(4)));   // MFMA acc

static __device__ __forceinline__ unsigned short f2bf(float f) {
    unsigned u = __builtin_bit_cast(unsigned, f);
    u += 0x7FFFu + ((u >> 16) & 1u);        // round-to-nearest-even
    return (unsigned short)(u >> 16);
}
static __device__ __forceinline__ float bflo(unsigned v) {
    return __builtin_bit_cast(float, v << 16);
}
static __device__ __forceinline__ float bfhi(unsigned v) {
    return __builtin_bit_cast(float, v & 0xFFFF0000u);
}

// ---------------------------------------------------------------------------
// prep: blocks [0,64) convert weights; blocks [64,846) zero cnt+ocount.
__global__ __launch_bounds__(256) void prep(const float* __restrict__ wn,
                                            const float* __restrict__ wsf,
                                            unsigned short* __restrict__ btn,
                                            unsigned short* __restrict__ bts,
                                            int4* __restrict__ cnt4)
{
    int b = blockIdx.x;
    if (b < WCONV_BLKS) {
        int idx = b * 256 + threadIdx.x;
        int k = idx >> 7, j = idx & 127;
        btn[(size_t)j * DIM + k] = f2bf(wn[idx]);                         // Wn^T
        bts[(size_t)j * DIM + k] = f2bf(wsf[idx] + (k == j ? 1.f : 0.f)); // (I+Ws)^T
    } else {
        int idx = (b - WCONV_BLKS) * 256 + threadIdx.x;
        if (idx < ZERO_INT4S) cnt4[idx] = make_int4(0, 0, 0, 0);
    }
}

// ---------------------------------------------------------------------------
// fill: 4 edges per thread, 3 coalesced int4 loads. Counters padded one per
// 64B line -> concurrent atomics pipeline across lines instead of serializing.
__global__ __launch_bounds__(256) void fill(const int* __restrict__ edges,
                                            int* __restrict__ cnt,
                                            unsigned* __restrict__ buckets,
                                            int* __restrict__ ocount,
                                            uint2* __restrict__ obuf)
{
    int t4 = blockIdx.x * 256 + threadIdx.x;
    if (t4 >= FILL_THREADS) return;
    const int4* ei = (const int4*)edges + (size_t)t4 * 3;
    int4 a = ei[0];
    int4 b = ei[1];
    int4 cc = ei[2];
    // layout: [s0 r0 d0 s1][r1 d1 s2 r2][d2 s3 r3 d3]
    int d0 = a.z,  d1 = b.y,  d2 = cc.x, d3 = cc.w;
    unsigned p0 = (unsigned)a.x  | ((unsigned)a.y  << 16);
    unsigned p1 = (unsigned)a.w  | ((unsigned)b.x  << 16);
    unsigned p2 = (unsigned)b.z  | ((unsigned)b.w  << 16);
    unsigned p3 = (unsigned)cc.y | ((unsigned)cc.z << 16);

    int q0 = atomicAdd(cnt + (size_t)d0 * CSTR, 1);
    int q1 = atomicAdd(cnt + (size_t)d1 * CSTR, 1);
    int q2 = atomicAdd(cnt + (size_t)d2 * CSTR, 1);
    int q3 = atomicAdd(cnt + (size_t)d3 * CSTR, 1);

    if (q0 < CAP) buckets[(size_t)d0 * CAP + q0] = p0;
    else { int o = atomicAdd(ocount, 1); if (o < OCAP) obuf[o] = make_uint2((unsigned)d0, p0); }
    if (q1 < CAP) buckets[(size_t)d1 * CAP + q1] = p1;
    else { int o = atomicAdd(ocount, 1); if (o < OCAP) obuf[o] = make_uint2((unsigned)d1, p1); }
    if (q2 < CAP) buckets[(size_t)d2 * CAP + q2] = p2;
    else { int o = atomicAdd(ocount, 1); if (o < OCAP) obuf[o] = make_uint2((unsigned)d2, p2); }
    if (q3 < CAP) buckets[(size_t)d3 * CAP + q3] = p3;
    else { int o = atomicAdd(ocount, 1); if (o < OCAP) obuf[o] = make_uint2((unsigned)d3, p3); }
}

// ---------------------------------------------------------------------------
// ts_kernel: fused two-phase GEMM, ONE aliased LDS buffer (34.8 KB), 4 blk/CU.
// ---------------------------------------------------------------------------
__global__ __launch_bounds__(256, 4) void ts_kernel(
    const float* __restrict__ nodes, const float* __restrict__ rels,
    const unsigned short* __restrict__ btn, const unsigned short* __restrict__ bts,
    unsigned short* __restrict__ T, unsigned short* __restrict__ U,
    float* __restrict__ Sp)
{
    __shared__ __align__(16) char ldsRaw[DIM * BP * 2];   // 34816 B
    unsigned short* ldsB = (unsigned short*)ldsRaw;
    unsigned short* ldsT = (unsigned short*)ldsRaw;       // aliased views
    float*          ldsS = (float*)ldsRaw;

    int blk = blockIdx.x;
    bool isRel = blk >= NODE_BLKS;
    const float* A = isRel ? rels : nodes;
    int nrows = isRel ? NRELS : NNODES;
    int rowbase = (isRel ? (blk - NODE_BLKS) : blk) * 64;

    int t  = threadIdx.x;
    int wv = t >> 6;
    int l  = t & 63;
    int r0 = rowbase + wv * 16;
    int m  = l & 15;
    int kg = l >> 4;
    int arow  = r0 + m;
    int arowc = arow < nrows ? arow : nrows - 1;

    s8f afrag[4];
    #pragma unroll
    for (int ks = 0; ks < 4; ++ks) {
        const float* p = A + (size_t)arowc * DIM + ks * 32 + kg * 8;
        float4 x = *(const float4*)p;
        float4 y = *(const float4*)(p + 4);
        s8f a;
        a[0] = (short)f2bf(x.x); a[1] = (short)f2bf(x.y);
        a[2] = (short)f2bf(x.z); a[3] = (short)f2bf(x.w);
        a[4] = (short)f2bf(y.x); a[5] = (short)f2bf(y.y);
        a[6] = (short)f2bf(y.z); a[7] = (short)f2bf(y.w);
        afrag[ks] = a;
    }

    // ---- phase 1: T/U = A @ Wn ----
    #pragma unroll
    for (int i = 0; i < 8; ++i) {                  // stage Wn^T
        int idx = t + i * 256;
        int col = idx >> 4, slot = idx & 15;
        *(uint4*)(ldsB + (size_t)col * BP + slot * 8) =
            *(const uint4*)(btn + (size_t)col * DIM + slot * 8);
    }
    __syncthreads();

    f4 acc[8];
    #pragma unroll
    for (int ct = 0; ct < 8; ++ct) {
        int col = ct * 16 + m;
        const unsigned short* bp = ldsB + (size_t)col * BP + kg * 8;
        f4 a = {0.f, 0.f, 0.f, 0.f};
        #pragma unroll
        for (int ks = 0; ks < 4; ++ks)
            a = __builtin_amdgcn_mfma_f32_16x16x32_bf16(afrag[ks], *(const s8f*)(bp + ks * 32), a, 0, 0, 0);
        acc[ct] = a;
    }
    __syncthreads();   // all ldsB reads done; safe to overwrite as ldsT

    #pragma unroll
    for (int ct = 0; ct < 8; ++ct)
        #pragma unroll
        for (int r = 0; r < 4; ++r)
            ldsT[((size_t)wv * 16 + kg * 4 + r) * TP + ct * 16 + m] = f2bf(acc[ct][r]);
    __syncthreads();

    unsigned short* Tout = isRel ? U : T;
    #pragma unroll
    for (int p = 0; p < 4; ++p) {
        int row = p * 4 + kg;
        int rg  = r0 + row;
        if (rg < nrows)
            *(uint4*)(Tout + (size_t)rg * DIM + m * 8) =
                *(const uint4*)&ldsT[((size_t)wv * 16 + row) * TP + m * 8];
    }
    if (isRel) return;   // whole block is rel -> uniform exit

    __syncthreads();   // ldsT reads done; safe to restage

    // ---- phase 2: Sp = A @ (I+Ws) ----
    #pragma unroll
    for (int i = 0; i < 8; ++i) {                  // stage (I+Ws)^T
        int idx = t + i * 256;
        int col = idx >> 4, slot = idx & 15;
        *(uint4*)(ldsB + (size_t)col * BP + slot * 8) =
            *(const uint4*)(bts + (size_t)col * DIM + slot * 8);
    }
    __syncthreads();

    #pragma unroll
    for (int ct = 0; ct < 8; ++ct) {
        int col = ct * 16 + m;
        const unsigned short* bp = ldsB + (size_t)col * BP + kg * 8;
        f4 a = {0.f, 0.f, 0.f, 0.f};
        #pragma unroll
        for (int ks = 0; ks < 4; ++ks)
            a = __builtin_amdgcn_mfma_f32_16x16x32_bf16(afrag[ks], *(const s8f*)(bp + ks * 32), a, 0, 0, 0);
        acc[ct] = a;
    }
    __syncthreads();   // ldsB reads done; overwrite as ldsS

    #pragma unroll
    for (int ct = 0; ct < 8; ++ct)
        #pragma unroll
        for (int r = 0; r < 4; ++r)
            ldsS[((size_t)wv * 16 + kg * 4 + r) * SP + ct * 16 + m] = acc[ct][r];
    __syncthreads();

    #pragma unroll
    for (int p = 0; p < 4; ++p) {
        int row = p * 4 + kg;
        int rg  = r0 + row;
        if (rg < NNODES) {
            float* orow = Sp + (size_t)rg * DIM;
            #pragma unroll
            for (int j = 0; j < 2; ++j) {
                int c0 = m * 4 + j * 64;
                *(float4*)(orow + c0) =
                    *(const float4*)&ldsS[((size_t)wv * 16 + row) * SP + c0];
            }
        }
    }
}

// ---------------------------------------------------------------------------
// gather: TWO nodes per wave (r13 structure, divergence-safe shfls).
// ---------------------------------------------------------------------------
#define ACCP(A, b) { \
    uint2 tt = *(const uint2*)(T + (size_t)((b) & 0xFFFFu) * DIM + c * 4); \
    uint2 uu = *(const uint2*)(U + (size_t)((b) >> 16)     * DIM + c * 4); \
    A.x += bflo(tt.x) + bflo(uu.x); A.y += bfhi(tt.x) + bfhi(uu.x); \
    A.z += bflo(tt.y) + bflo(uu.y); A.w += bfhi(tt.y) + bfhi(uu.y); }

#define BATCH(my, degc, A) \
    if (jb < degc) { \
        unsigned b0 = __shfl(my, j0,     64); \
        unsigned b1 = __shfl(my, j0 + 2, 64); \
        unsigned b2 = __shfl(my, j0 + 4, 64); \
        unsigned b3 = __shfl(my, j0 + 6, 64); \
        if (jb + 8 <= degc) { ACCP(A, b0); ACCP(A, b1); ACCP(A, b2); ACCP(A, b3); } \
        else { \
            if (j0     < degc) ACCP(A, b0); \
            if (j0 + 2 < degc) ACCP(A, b1); \
            if (j0 + 4 < degc) ACCP(A, b2); \
            if (j0 + 6 < degc) ACCP(A, b3); } }

__global__ __launch_bounds__(256) void gather(
    const unsigned short* __restrict__ T, const unsigned short* __restrict__ U,
    const int* __restrict__ cnt, const unsigned* __restrict__ buckets,
    const int* __restrict__ ocount, const uint2* __restrict__ obuf,
    const float* __restrict__ nodes, const float* __restrict__ wse,
    float* __restrict__ outp)
{
    int wid = (blockIdx.x * 256 + threadIdx.x) >> 6;
    if (wid >= NNODES / 2) return;
    int n0 = wid * 2;
    int n1 = n0 + 1;
    int l = threadIdx.x & 63;
    int half = l >> 5;
    int c = l & 31;

    int deg0 = cnt[(size_t)n0 * CSTR];   // wave-uniform (padded counters)
    int deg1 = cnt[(size_t)n1 * CSTR];   // wave-uniform
    int degc0 = deg0 < CAP ? deg0 : CAP;
    int degc1 = deg1 < CAP ? deg1 : CAP;

    // independent prologue loads: both bucket rows + this half's Sp row
    unsigned my0 = (l < degc0) ? buckets[(size_t)n0 * CAP + l] : 0u;
    unsigned my1 = (l < degc1) ? buckets[(size_t)n1 * CAP + l] : 0u;
    int nm = half ? n1 : n0;
    float4 spm = *(const float4*)(outp + (size_t)nm * DIM + c * 4);

    float4 acc0 = make_float4(0.f, 0.f, 0.f, 0.f);
    float4 acc1 = make_float4(0.f, 0.f, 0.f, 0.f);
    int maxd = degc0 > degc1 ? degc0 : degc1;
    for (int jb = 0; jb < maxd; jb += 8) {   // wave-uniform condition
        int j0 = jb + half;
        BATCH(my0, degc0, acc0);             // wave-uniform guard
        BATCH(my1, degc1, acc1);             // independent -> overlapped loads
    }

    if ((deg0 > CAP) || (deg1 > CAP)) {      // wave-uniform, ~never taken
        int oc = *ocount;
        if (oc > OCAP) oc = OCAP;
        for (int k = 0; k < oc; ++k) {
            uint2 e = obuf[k];
            if ((int)e.x == n0 && (k & 1) == half) ACCP(acc0, e.y);
            if ((int)e.x == n1 && (k & 1) == half) ACCP(acc1, e.y);
        }
    }

    // cross-half reductions at full-wave activity
    acc0.x += __shfl_xor(acc0.x, 32, 64);
    acc0.y += __shfl_xor(acc0.y, 32, 64);
    acc0.z += __shfl_xor(acc0.z, 32, 64);
    acc0.w += __shfl_xor(acc0.w, 32, 64);
    acc1.x += __shfl_xor(acc1.x, 32, 64);
    acc1.y += __shfl_xor(acc1.y, 32, 64);
    acc1.z += __shfl_xor(acc1.z, 32, 64);
    acc1.w += __shfl_xor(acc1.w, 32, 64);

    // epilogue: each half writes its own node's row (divergent stores only)
    float4 am = half ? acc1 : acc0;
    int dm = half ? deg1 : deg0;
    if (dm > 0) {
        float inv = 1.0f / (float)dm;
        float4 o = { spm.x + am.x * inv, spm.y + am.y * inv,
                     spm.z + am.z * inv, spm.w + am.w * inv };
        *(float4*)(outp + (size_t)nm * DIM + c * 4) = o;
    }

    // rare deg==0 fallback: out = h + h @ Wse (wave-uniform branches)
    if (deg0 == 0 && half == 0) {
        float s0 = 0, s1 = 0, s2 = 0, s3 = 0;
        for (int k = 0; k < DIM; ++k) {
            float hk = nodes[(size_t)n0 * DIM + k];
            const float* wr = wse + (size_t)k * DIM + c * 4;
            s0 += hk * wr[0]; s1 += hk * wr[1];
            s2 += hk * wr[2]; s3 += hk * wr[3];
        }
        float4 hv = *(const float4*)(nodes + (size_t)n0 * DIM + c * 4);
        float4 o = { hv.x + s0, hv.y + s1, hv.z + s2, hv.w + s3 };
        *(float4*)(outp + (size_t)n0 * DIM + c * 4) = o;
    }
    if (deg1 == 0 && half == 1) {
        float s0 = 0, s1 = 0, s2 = 0, s3 = 0;
        for (int k = 0; k < DIM; ++k) {
            float hk = nodes[(size_t)n1 * DIM + k];
            const float* wr = wse + (size_t)k * DIM + c * 4;
            s0 += hk * wr[0]; s1 += hk * wr[1];
            s2 += hk * wr[2]; s3 += hk * wr[3];
        }
        float4 hv = *(const float4*)(nodes + (size_t)n1 * DIM + c * 4);
        float4 o = { hv.x + s0, hv.y + s1, hv.z + s2, hv.w + s3 };
        *(float4*)(outp + (size_t)n1 * DIM + c * 4) = o;
    }
}

// ---------------------------------------------------------------------------
extern "C" void kernel_launch(void* const* d_in, const int* in_sizes, int n_in,
                              void* d_out, int out_size, void* d_ws, size_t ws_size,
                              hipStream_t stream)
{
    const float* nodes = (const float*)d_in[0];
    const float* rels  = (const float*)d_in[1];
    const int*   edges = (const int*)d_in[2];
    const float* wn    = (const float*)d_in[3];
    const float* wsf   = (const float*)d_in[4];
    const float* wse   = (const float*)d_in[5];
    float* out = (float*)d_out;

    char* ws = (char*)d_ws;
    int*            cnt     = (int*)(ws + OFF_CNT_B);
    int*            ocount  = (int*)(ws + OFF_OCNT_B);
    uint2*          obuf    = (uint2*)(ws + OFF_OBUF_B);
    unsigned*       buckets = (unsigned*)(ws + OFF_BKT_B);
    unsigned short* btn     = (unsigned short*)(ws + OFF_BTN_B);
    unsigned short* bts     = (unsigned short*)(ws + OFF_BTS_B);
    unsigned short* T       = (unsigned short*)(ws + OFF_T_B);
    unsigned short* U       = (unsigned short*)(ws + OFF_U_B);

    prep<<<PREP_BLKS, 256, 0, stream>>>(wn, wsf, btn, bts, (int4*)cnt);

    fill<<<FILL_BLKS, 256, 0, stream>>>(edges, cnt, buckets, ocount, obuf);

    ts_kernel<<<TS_BLKS, 256, 0, stream>>>(nodes, rels, btn, bts, T, U, out);

    gather<<<GATHER_BLKS, 256, 0, stream>>>(T, U, cnt, buckets, ocount, obuf, nodes, wse, out);
}

// Round 15
// 91.103 us; speedup vs baseline: 1.1846x; 1.0192x over previous
//
#include <hip/hip_runtime.h>

// URGCN layer, MI355X — round 15.
// r14 post-mortem: fill is bound by atomic-WITH-RETURN round trips (~900cy to
// the shared atomic point); fire-and-forget runs 5x faster (r0: 74 G/s).
// Fix: fuse fill INTO ts as issue-early/use-late — atomics issued at block
// start, returned slots consumed for the scattered stores only AFTER the
// GEMM epilogue (latency hidden under compute). Every block does both roles
// (r11's LDS-starved fill-only blocks don't exist here).
// gather: VGPR=32 showed serialized load chains -> fast loop stages 16 loads
// in explicit locals before accumulating (guarded tail keeps r11 semantics).
//
// Algebra: msg_agg = (Σ_e T[src] + u[rel]) / deg, T = h@Wn (bf16 MFMA),
//          u = rel@Wn.  out = Sp + msg_agg, Sp = h@(I+Wself) (f32, in d_out).

constexpr int NNODES = 50000;
constexpr int NEDGES = 600000;
constexpr int NRELS  = 500;
constexpr int DIM    = 128;
constexpr int CAP    = 48;      // bucket capacity per node
constexpr int OCAP   = 8192;    // overflow list capacity
constexpr int CSTR   = 16;      // cnt stride in ints (64B line per counter)

constexpr int NODE_BLKS = (NNODES + 63) / 64;   // 782
constexpr int REL_BLKS  = (NRELS  + 63) / 64;   // 8
constexpr int TS_BLKS   = NODE_BLKS + REL_BLKS; // 790

constexpr int BP = 136;   // LDS B row pitch (shorts)
constexpr int TP = 136;   // LDS T tile pitch (shorts)
constexpr int SP = 132;   // LDS S tile pitch (floats)

// prep geometry: zero cnt[50000*16] + ocount -> 200001 int4
constexpr int WCONV_BLKS = (DIM * DIM + 255) / 256;            // 64
constexpr int ZERO_INT4S = 200001;
constexpr int ZERO_BLKS  = (ZERO_INT4S + 255) / 256;           // 782
constexpr int PREP_BLKS  = WCONV_BLKS + ZERO_BLKS;             // 846

// fill geometry: 4 edges/thread over the first FILL_BLKS blocks of fillts
constexpr int FILL_THREADS = NEDGES / 4;                       // 150000
constexpr int FILL_BLKS    = (FILL_THREADS + 255) / 256;       // 586

// gather geometry: 2 nodes per wave
constexpr int GATHER_BLKS  = (NNODES / 2 * 64) / 256;          // 6250

// ---------------- workspace layout (bytes) ----------------
constexpr size_t OFF_CNT_B  = 0;          // int[50000*16] padded counters
constexpr size_t OFF_OCNT_B = 3200000;    // int ocount
constexpr size_t OFF_OBUF_B = 3204800;    // uint2[8192]
constexpr size_t OFF_BKT_B  = 3270336;    // uint[50000*48]
constexpr size_t OFF_BTN_B  = OFF_BKT_B + (size_t)NNODES * CAP * 4;
constexpr size_t OFF_BTS_B  = OFF_BTN_B + 32768;
constexpr size_t OFF_T_B    = OFF_BTS_B + 32768;
constexpr size_t OFF_U_B    = OFF_T_B + (size_t)NNODES * DIM * 2;

typedef short s8f __attribute__((ext_vector_type(8)));   // 8 bf16
typedef float f4  __attribute__((ext_vector_type(4)));   // MFMA acc

static __device__ __forceinline__ unsigned short f2bf(float f) {
    unsigned u = __builtin_bit_cast(unsigned, f);
    u += 0x7FFFu + ((u >> 16) & 1u);
    return (unsigned short)(u >> 16);
}
static __device__ __forceinline__ float bflo(unsigned v) {
    return __builtin_bit_cast(float, v << 16);
}
static __device__ __forceinline__ float bfhi(unsigned v) {
    return __builtin_bit_cast(float, v & 0xFFFF0000u);
}

// ---------------------------------------------------------------------------
__global__ __launch_bounds__(256) void prep(const float* __restrict__ wn,
                                            const float* __restrict__ wsf,
                                            unsigned short* __restrict__ btn,
                                            unsigned short* __restrict__ bts,
                                            int4* __restrict__ cnt4)
{
    int b = blockIdx.x;
    if (b < WCONV_BLKS) {
        int idx = b * 256 + threadIdx.x;
        int k = idx >> 7, j = idx & 127;
        btn[(size_t)j * DIM + k] = f2bf(wn[idx]);                         // Wn^T
        bts[(size_t)j * DIM + k] = f2bf(wsf[idx] + (k == j ? 1.f : 0.f)); // (I+Ws)^T
    } else {
        int idx = (b - WCONV_BLKS) * 256 + threadIdx.x;
        if (idx < ZERO_INT4S) cnt4[idx] = make_int4(0, 0, 0, 0);
    }
}

// ---------------------------------------------------------------------------
// fillts: fused. Blocks [0,586) additionally own 4 edges/thread:
//   START: load edges, issue 4 atomicAdd (returns in flight)
//   MIDDLE: the full two-phase GEMM (T/U then Sp)
//   END: consume returned slots -> scattered bucket stores (latency hidden)
// ---------------------------------------------------------------------------
__global__ __launch_bounds__(256, 4) void fillts(
    const int* __restrict__ edges,
    int* __restrict__ cnt, unsigned* __restrict__ buckets,
    int* __restrict__ ocount, uint2* __restrict__ obuf,
    const float* __restrict__ nodes, const float* __restrict__ rels,
    const unsigned short* __restrict__ btn, const unsigned short* __restrict__ bts,
    unsigned short* __restrict__ T, unsigned short* __restrict__ U,
    float* __restrict__ Sp)
{
    __shared__ __align__(16) char ldsRaw[DIM * BP * 2];   // 34816 B
    unsigned short* ldsB = (unsigned short*)ldsRaw;
    unsigned short* ldsT = (unsigned short*)ldsRaw;
    float*          ldsS = (float*)ldsRaw;

    int blk = blockIdx.x;
    int t   = threadIdx.x;

    // ---- fill issue phase ----
    bool doFill = false;
    int d0 = 0, d1 = 0, d2 = 0, d3 = 0;
    unsigned p0 = 0, p1 = 0, p2 = 0, p3 = 0;
    int q0 = 0, q1 = 0, q2 = 0, q3 = 0;
    if (blk < FILL_BLKS) {
        int t4 = blk * 256 + t;
        if (t4 < FILL_THREADS) {
            doFill = true;
            const int4* ei = (const int4*)edges + (size_t)t4 * 3;
            int4 a = ei[0];
            int4 b = ei[1];
            int4 cc = ei[2];
            // [s0 r0 d0 s1][r1 d1 s2 r2][d2 s3 r3 d3]
            d0 = a.z;  d1 = b.y;  d2 = cc.x; d3 = cc.w;
            p0 = (unsigned)a.x  | ((unsigned)a.y  << 16);
            p1 = (unsigned)a.w  | ((unsigned)b.x  << 16);
            p2 = (unsigned)b.z  | ((unsigned)b.w  << 16);
            p3 = (unsigned)cc.y | ((unsigned)cc.z << 16);
            q0 = atomicAdd(cnt + (size_t)d0 * CSTR, 1);
            q1 = atomicAdd(cnt + (size_t)d1 * CSTR, 1);
            q2 = atomicAdd(cnt + (size_t)d2 * CSTR, 1);
            q3 = atomicAdd(cnt + (size_t)d3 * CSTR, 1);
        }
    }

    // ---- GEMM ----
    bool isRel = blk >= NODE_BLKS;
    const float* A = isRel ? rels : nodes;
    int nrows = isRel ? NRELS : NNODES;
    int rowbase = (isRel ? (blk - NODE_BLKS) : blk) * 64;

    int wv = t >> 6;
    int l  = t & 63;
    int r0 = rowbase + wv * 16;
    int m  = l & 15;
    int kg = l >> 4;
    int arow  = r0 + m;
    int arowc = arow < nrows ? arow : nrows - 1;

    s8f afrag[4];
    #pragma unroll
    for (int ks = 0; ks < 4; ++ks) {
        const float* p = A + (size_t)arowc * DIM + ks * 32 + kg * 8;
        float4 x = *(const float4*)p;
        float4 y = *(const float4*)(p + 4);
        s8f a;
        a[0] = (short)f2bf(x.x); a[1] = (short)f2bf(x.y);
        a[2] = (short)f2bf(x.z); a[3] = (short)f2bf(x.w);
        a[4] = (short)f2bf(y.x); a[5] = (short)f2bf(y.y);
        a[6] = (short)f2bf(y.z); a[7] = (short)f2bf(y.w);
        afrag[ks] = a;
    }

    // phase 1: T/U = A @ Wn
    #pragma unroll
    for (int i = 0; i < 8; ++i) {
        int idx = t + i * 256;
        int col = idx >> 4, slot = idx & 15;
        *(uint4*)(ldsB + (size_t)col * BP + slot * 8) =
            *(const uint4*)(btn + (size_t)col * DIM + slot * 8);
    }
    __syncthreads();

    f4 acc[8];
    #pragma unroll
    for (int ct = 0; ct < 8; ++ct) {
        int col = ct * 16 + m;
        const unsigned short* bp = ldsB + (size_t)col * BP + kg * 8;
        f4 a = {0.f, 0.f, 0.f, 0.f};
        #pragma unroll
        for (int ks = 0; ks < 4; ++ks)
            a = __builtin_amdgcn_mfma_f32_16x16x32_bf16(afrag[ks], *(const s8f*)(bp + ks * 32), a, 0, 0, 0);
        acc[ct] = a;
    }
    __syncthreads();

    #pragma unroll
    for (int ct = 0; ct < 8; ++ct)
        #pragma unroll
        for (int r = 0; r < 4; ++r)
            ldsT[((size_t)wv * 16 + kg * 4 + r) * TP + ct * 16 + m] = f2bf(acc[ct][r]);
    __syncthreads();

    unsigned short* Tout = isRel ? U : T;
    #pragma unroll
    for (int p = 0; p < 4; ++p) {
        int row = p * 4 + kg;
        int rg  = r0 + row;
        if (rg < nrows)
            *(uint4*)(Tout + (size_t)rg * DIM + m * 8) =
                *(const uint4*)&ldsT[((size_t)wv * 16 + row) * TP + m * 8];
    }

    if (!isRel) {
        __syncthreads();
        // phase 2: Sp = A @ (I+Ws)
        #pragma unroll
        for (int i = 0; i < 8; ++i) {
            int idx = t + i * 256;
            int col = idx >> 4, slot = idx & 15;
            *(uint4*)(ldsB + (size_t)col * BP + slot * 8) =
                *(const uint4*)(bts + (size_t)col * DIM + slot * 8);
        }
        __syncthreads();

        #pragma unroll
        for (int ct = 0; ct < 8; ++ct) {
            int col = ct * 16 + m;
            const unsigned short* bp = ldsB + (size_t)col * BP + kg * 8;
            f4 a = {0.f, 0.f, 0.f, 0.f};
            #pragma unroll
            for (int ks = 0; ks < 4; ++ks)
                a = __builtin_amdgcn_mfma_f32_16x16x32_bf16(afrag[ks], *(const s8f*)(bp + ks * 32), a, 0, 0, 0);
            acc[ct] = a;
        }
        __syncthreads();

        #pragma unroll
        for (int ct = 0; ct < 8; ++ct)
            #pragma unroll
            for (int r = 0; r < 4; ++r)
                ldsS[((size_t)wv * 16 + kg * 4 + r) * SP + ct * 16 + m] = acc[ct][r];
        __syncthreads();

        #pragma unroll
        for (int p = 0; p < 4; ++p) {
            int row = p * 4 + kg;
            int rg  = r0 + row;
            if (rg < NNODES) {
                float* orow = Sp + (size_t)rg * DIM;
                #pragma unroll
                for (int j = 0; j < 2; ++j) {
                    int c0 = m * 4 + j * 64;
                    *(float4*)(orow + c0) =
                        *(const float4*)&ldsS[((size_t)wv * 16 + row) * SP + c0];
                }
            }
        }
    }

    // ---- fill store phase: atomic results returned long ago ----
    if (doFill) {
        if (q0 < CAP) buckets[(size_t)d0 * CAP + q0] = p0;
        else { int o = atomicAdd(ocount, 1); if (o < OCAP) obuf[o] = make_uint2((unsigned)d0, p0); }
        if (q1 < CAP) buckets[(size_t)d1 * CAP + q1] = p1;
        else { int o = atomicAdd(ocount, 1); if (o < OCAP) obuf[o] = make_uint2((unsigned)d1, p1); }
        if (q2 < CAP) buckets[(size_t)d2 * CAP + q2] = p2;
        else { int o = atomicAdd(ocount, 1); if (o < OCAP) obuf[o] = make_uint2((unsigned)d2, p2); }
        if (q3 < CAP) buckets[(size_t)d3 * CAP + q3] = p3;
        else { int o = atomicAdd(ocount, 1); if (o < OCAP) obuf[o] = make_uint2((unsigned)d3, p3); }
    }
}

// ---------------------------------------------------------------------------
// gather: TWO nodes per wave. Fast loop (both nodes have a full batch):
// UNGUARDED — 8 shfls then 16 loads staged in explicit locals (clustered
// issue), then accumulate. Tail loop keeps the guarded divergence-safe form.
// ---------------------------------------------------------------------------
#define LDT(b) (*(const uint2*)(T + (size_t)((b) & 0xFFFFu) * DIM + c * 4))
#define LDU(b) (*(const uint2*)(U + (size_t)((b) >> 16)     * DIM + c * 4))
#define ADD2(A, tt, uu) { \
    A.x += bflo(tt.x) + bflo(uu.x); A.y += bfhi(tt.x) + bfhi(uu.x); \
    A.z += bflo(tt.y) + bflo(uu.y); A.w += bfhi(tt.y) + bfhi(uu.y); }
#define ACCP(A, b) { uint2 tt = LDT(b); uint2 uu = LDU(b); ADD2(A, tt, uu); }

#define BATCH(my, degc, A) \
    if (jb < degc) { \
        unsigned b0 = __shfl(my, j0,     64); \
        unsigned b1 = __shfl(my, j0 + 2, 64); \
        unsigned b2 = __shfl(my, j0 + 4, 64); \
        unsigned b3 = __shfl(my, j0 + 6, 64); \
        if (jb + 8 <= degc) { ACCP(A, b0); ACCP(A, b1); ACCP(A, b2); ACCP(A, b3); } \
        else { \
            if (j0     < degc) ACCP(A, b0); \
            if (j0 + 2 < degc) ACCP(A, b1); \
            if (j0 + 4 < degc) ACCP(A, b2); \
            if (j0 + 6 < degc) ACCP(A, b3); } }

__global__ __launch_bounds__(256) void gather(
    const unsigned short* __restrict__ T, const unsigned short* __restrict__ U,
    const int* __restrict__ cnt, const unsigned* __restrict__ buckets,
    const int* __restrict__ ocount, const uint2* __restrict__ obuf,
    const float* __restrict__ nodes, const float* __restrict__ wse,
    float* __restrict__ outp)
{
    int wid = (blockIdx.x * 256 + threadIdx.x) >> 6;
    if (wid >= NNODES / 2) return;
    int n0 = wid * 2;
    int n1 = n0 + 1;
    int l = threadIdx.x & 63;
    int half = l >> 5;
    int c = l & 31;

    int deg0 = cnt[(size_t)n0 * CSTR];   // wave-uniform
    int deg1 = cnt[(size_t)n1 * CSTR];
    int degc0 = deg0 < CAP ? deg0 : CAP;
    int degc1 = deg1 < CAP ? deg1 : CAP;

    unsigned my0 = (l < degc0) ? buckets[(size_t)n0 * CAP + l] : 0u;
    unsigned my1 = (l < degc1) ? buckets[(size_t)n1 * CAP + l] : 0u;
    int nm = half ? n1 : n0;
    float4 spm = *(const float4*)(outp + (size_t)nm * DIM + c * 4);

    float4 acc0 = make_float4(0.f, 0.f, 0.f, 0.f);
    float4 acc1 = make_float4(0.f, 0.f, 0.f, 0.f);

    int minfull = (degc0 < degc1 ? degc0 : degc1) & ~7;  // wave-uniform
    int jb = 0;
    for (; jb < minfull; jb += 8) {
        int j0 = jb + half;
        // 8 shfls at full-wave activity
        unsigned b0 = __shfl(my0, j0,     64);
        unsigned b1 = __shfl(my0, j0 + 2, 64);
        unsigned b2 = __shfl(my0, j0 + 4, 64);
        unsigned b3 = __shfl(my0, j0 + 6, 64);
        unsigned b4 = __shfl(my1, j0,     64);
        unsigned b5 = __shfl(my1, j0 + 2, 64);
        unsigned b6 = __shfl(my1, j0 + 4, 64);
        unsigned b7 = __shfl(my1, j0 + 6, 64);
        // 16 loads staged before any use -> clustered issue
        uint2 t0 = LDT(b0), t1 = LDT(b1), t2 = LDT(b2), t3 = LDT(b3);
        uint2 t4 = LDT(b4), t5 = LDT(b5), t6 = LDT(b6), t7 = LDT(b7);
        uint2 u0 = LDU(b0), u1 = LDU(b1), u2 = LDU(b2), u3 = LDU(b3);
        uint2 u4 = LDU(b4), u5 = LDU(b5), u6 = LDU(b6), u7 = LDU(b7);
        ADD2(acc0, t0, u0); ADD2(acc0, t1, u1);
        ADD2(acc0, t2, u2); ADD2(acc0, t3, u3);
        ADD2(acc1, t4, u4); ADD2(acc1, t5, u5);
        ADD2(acc1, t6, u6); ADD2(acc1, t7, u7);
    }

    int maxd = degc0 > degc1 ? degc0 : degc1;
    for (; jb < maxd; jb += 8) {             // guarded tail (wave-uniform)
        int j0 = jb + half;
        BATCH(my0, degc0, acc0);
        BATCH(my1, degc1, acc1);
    }

    if ((deg0 > CAP) || (deg1 > CAP)) {      // ~never taken
        int oc = *ocount;
        if (oc > OCAP) oc = OCAP;
        for (int k = 0; k < oc; ++k) {
            uint2 e = obuf[k];
            if ((int)e.x == n0 && (k & 1) == half) ACCP(acc0, e.y);
            if ((int)e.x == n1 && (k & 1) == half) ACCP(acc1, e.y);
        }
    }

    acc0.x += __shfl_xor(acc0.x, 32, 64);
    acc0.y += __shfl_xor(acc0.y, 32, 64);
    acc0.z += __shfl_xor(acc0.z, 32, 64);
    acc0.w += __shfl_xor(acc0.w, 32, 64);
    acc1.x += __shfl_xor(acc1.x, 32, 64);
    acc1.y += __shfl_xor(acc1.y, 32, 64);
    acc1.z += __shfl_xor(acc1.z, 32, 64);
    acc1.w += __shfl_xor(acc1.w, 32, 64);

    float4 am = half ? acc1 : acc0;
    int dm = half ? deg1 : deg0;
    if (dm > 0) {
        float inv = 1.0f / (float)dm;
        float4 o = { spm.x + am.x * inv, spm.y + am.y * inv,
                     spm.z + am.z * inv, spm.w + am.w * inv };
        *(float4*)(outp + (size_t)nm * DIM + c * 4) = o;
    }

    if (deg0 == 0 && half == 0) {
        float s0 = 0, s1 = 0, s2 = 0, s3 = 0;
        for (int k = 0; k < DIM; ++k) {
            float hk = nodes[(size_t)n0 * DIM + k];
            const float* wr = wse + (size_t)k * DIM + c * 4;
            s0 += hk * wr[0]; s1 += hk * wr[1];
            s2 += hk * wr[2]; s3 += hk * wr[3];
        }
        float4 hv = *(const float4*)(nodes + (size_t)n0 * DIM + c * 4);
        float4 o = { hv.x + s0, hv.y + s1, hv.z + s2, hv.w + s3 };
        *(float4*)(outp + (size_t)n0 * DIM + c * 4) = o;
    }
    if (deg1 == 0 && half == 1) {
        float s0 = 0, s1 = 0, s2 = 0, s3 = 0;
        for (int k = 0; k < DIM; ++k) {
            float hk = nodes[(size_t)n1 * DIM + k];
            const float* wr = wse + (size_t)k * DIM + c * 4;
            s0 += hk * wr[0]; s1 += hk * wr[1];
            s2 += hk * wr[2]; s3 += hk * wr[3];
        }
        float4 hv = *(const float4*)(nodes + (size_t)n1 * DIM + c * 4);
        float4 o = { hv.x + s0, hv.y + s1, hv.z + s2, hv.w + s3 };
        *(float4*)(outp + (size_t)n1 * DIM + c * 4) = o;
    }
}

// ---------------------------------------------------------------------------
extern "C" void kernel_launch(void* const* d_in, const int* in_sizes, int n_in,
                              void* d_out, int out_size, void* d_ws, size_t ws_size,
                              hipStream_t stream)
{
    const float* nodes = (const float*)d_in[0];
    const float* rels  = (const float*)d_in[1];
    const int*   edges = (const int*)d_in[2];
    const float* wn    = (const float*)d_in[3];
    const float* wsf   = (const float*)d_in[4];
    const float* wse   = (const float*)d_in[5];
    float* out = (float*)d_out;

    char* ws = (char*)d_ws;
    int*            cnt     = (int*)(ws + OFF_CNT_B);
    int*            ocount  = (int*)(ws + OFF_OCNT_B);
    uint2*          obuf    = (uint2*)(ws + OFF_OBUF_B);
    unsigned*       buckets = (unsigned*)(ws + OFF_BKT_B);
    unsigned short* btn     = (unsigned short*)(ws + OFF_BTN_B);
    unsigned short* bts     = (unsigned short*)(ws + OFF_BTS_B);
    unsigned short* T       = (unsigned short*)(ws + OFF_T_B);
    unsigned short* U       = (unsigned short*)(ws + OFF_U_B);

    prep<<<PREP_BLKS, 256, 0, stream>>>(wn, wsf, btn, bts, (int4*)cnt);

    fillts<<<TS_BLKS, 256, 0, stream>>>(edges, cnt, buckets, ocount, obuf,
                                        nodes, rels, btn, bts, T, U, out);

    gather<<<GATHER_BLKS, 256, 0, stream>>>(T, U, cnt, buckets, ocount, obuf,
                                            nodes, wse, out);
}